// Round 2
// baseline (647.846 us; speedup 1.0000x reference)
//
#include <hip/hip_runtime.h>
#include <hip/hip_bf16.h>
#include <math.h>

using bf16_t = __bf16;
using bf16x8 = __attribute__((ext_vector_type(8))) __bf16;
using f32x4  = __attribute__((ext_vector_type(4))) float;

typedef __attribute__((address_space(1))) const void* gas_ptr;
typedef __attribute__((address_space(3))) void*       las_ptr;

// ---------------------------------------------------------------------------
// Problem constants
// ---------------------------------------------------------------------------
#define BATCH    2
#define SEQ      2048
#define DMODEL   2048
#define DINNER   4096
#define DSTATE   16
#define NROWS    (BATCH * SEQ)          // 4096

// ---------------------------------------------------------------------------
// fp32 -> bf16 cast (8 elems / thread)
// ---------------------------------------------------------------------------
__global__ void cast_kernel(const float* __restrict__ src, bf16_t* __restrict__ dst, int n)
{
    int idx = (blockIdx.x * 256 + threadIdx.x) * 8;
    if (idx >= n) return;
    float4 a = *(const float4*)(src + idx);
    float4 b = *(const float4*)(src + idx + 4);
    bf16x8 o;
    o[0] = (bf16_t)a.x; o[1] = (bf16_t)a.y; o[2] = (bf16_t)a.z; o[3] = (bf16_t)a.w;
    o[4] = (bf16_t)b.x; o[5] = (bf16_t)b.y; o[6] = (bf16_t)b.z; o[7] = (bf16_t)b.w;
    *(bf16x8*)(dst + idx) = o;
}

// ---------------------------------------------------------------------------
// bf16 GEMM  C = A(MxK, row-major) * B(NxK, row-major)^T
// 128x128 tile, BK=64, 4 waves, mfma_f32_16x16x32_bf16, 4x4 acc/wave.
// Staging via global_load_lds width=16 (m97 structure): LDS dest is
// wave-uniform base + lane*16 -> LDS layout MUST be unpadded (LDK=64).
// Per wave per K-iter: 4 chunks A + 4 chunks B (1024 B each).
// MODE 0 (GEMM1): N=8192; col<4096 -> xi fp32 ; col>=4096 -> sigmoid -> g bf16
// MODE 1 (GEMM2): N=2048; out[row][col] = acc * (4096 * rowscale[row])
// ---------------------------------------------------------------------------
template <int MODE>
__global__ __launch_bounds__(256)
void gemm_bt(const bf16_t* __restrict__ A, const bf16_t* __restrict__ B, int K,
             float* __restrict__ outf, bf16_t* __restrict__ outg,
             const float* __restrict__ rowscale)
{
    constexpr int LDK = 64;            // unpadded: required by global_load_lds
    __shared__ bf16_t As[128 * LDK];
    __shared__ bf16_t Bs[128 * LDK];

    const int t    = threadIdx.x;
    const int m0   = blockIdx.y * 128;
    const int n0   = blockIdx.x * 128;
    const int w    = t >> 6;
    const int lane = t & 63;
    const int wr   = (w >> 1) * 64;
    const int wc   = (w & 1) * 64;
    const int lo   = lane & 15;
    const int q    = lane >> 4;

    // staging geometry: wave w covers rows [w*32, w*32+32); chunk c = 8 rows.
    // lane i -> row +(i>>3), elem col (i&7)*8; LDS dest = uniform chunk base.
    const int srow = w * 32 + (lane >> 3);
    const int scol = (lane & 7) * 8;
    const bf16_t* gA = A + (size_t)(m0 + srow) * K + scol;
    const bf16_t* gB = B + (size_t)(n0 + srow) * K + scol;

    f32x4 acc[4][4];
#pragma unroll
    for (int i = 0; i < 4; ++i)
#pragma unroll
        for (int j = 0; j < 4; ++j) acc[i][j] = (f32x4){0.f, 0.f, 0.f, 0.f};

    for (int k0 = 0; k0 < K; k0 += 64) {
#pragma unroll
        for (int c = 0; c < 4; ++c) {
            const size_t go = (size_t)c * 8 * K;          // +8 rows per chunk
            const int    lo_off = (w * 32 + c * 8) * LDK; // wave-uniform
            __builtin_amdgcn_global_load_lds((gas_ptr)(gA + go), (las_ptr)&As[lo_off], 16, 0, 0);
            __builtin_amdgcn_global_load_lds((gas_ptr)(gB + go), (las_ptr)&Bs[lo_off], 16, 0, 0);
        }
        gA += 64; gB += 64;
        __syncthreads();                                  // drains vmcnt too

#pragma unroll
        for (int ks = 0; ks < 2; ++ks) {
            const int kk = ks * 32 + q * 8;
            bf16x8 af[4], bfv[4];
#pragma unroll
            for (int mi = 0; mi < 4; ++mi)
                af[mi] = *(const bf16x8*)&As[(wr + mi * 16 + lo) * LDK + kk];
#pragma unroll
            for (int ni = 0; ni < 4; ++ni)
                bfv[ni] = *(const bf16x8*)&Bs[(wc + ni * 16 + lo) * LDK + kk];
#pragma unroll
            for (int mi = 0; mi < 4; ++mi)
#pragma unroll
                for (int ni = 0; ni < 4; ++ni)
                    acc[mi][ni] = __builtin_amdgcn_mfma_f32_16x16x32_bf16(
                        af[mi], bfv[ni], acc[mi][ni], 0, 0, 0);
        }
        __syncthreads();
    }

    // epilogue: C/D layout col = lane&15, row = quad*4 + reg  [m89/m91 verified]
#pragma unroll
    for (int mi = 0; mi < 4; ++mi) {
#pragma unroll
        for (int ni = 0; ni < 4; ++ni) {
            const int col   = n0 + wc + ni * 16 + lo;
            const int rbase = m0 + wr + mi * 16 + q * 4;
#pragma unroll
            for (int rr = 0; rr < 4; ++rr) {
                float v   = acc[mi][ni][rr];
                int   row = rbase + rr;
                if (MODE == 0) {
                    if (col < DINNER) {
                        outf[(size_t)row * DINNER + col] = v;            // xi fp32
                    } else {
                        float sg = 1.f / (1.f + __expf(-v));             // sigmoid(gate)
                        outg[(size_t)row * DINNER + (col - DINNER)] = (bf16_t)sg;
                    }
                } else {
                    outf[(size_t)row * DMODEL + col] = v * (4096.0f * rowscale[row]);
                }
            }
        }
    }
}

// ---------------------------------------------------------------------------
// depthwise causal conv(4) + SiLU.  Writes xs (bf16, all 4096 ch) and
// uT[b][c][s] fp32 for c<16 (transposed for the scan).
// ---------------------------------------------------------------------------
__global__ void conv_silu_kernel(const float* __restrict__ xi, const float* __restrict__ cw,
                                 const float* __restrict__ cb, bf16_t* __restrict__ xs,
                                 float* __restrict__ uT)
{
    int idx = blockIdx.x * 256 + threadIdx.x;   // < 16,777,216
    int r = idx >> 12;
    int c = idx & 4095;
    int s = r & (SEQ - 1);
    int b = r >> 11;

    float4 wt = *(const float4*)(cw + c * 4);   // taps k=0..3 -> inputs s-3..s
    const float* p = xi + (size_t)r * DINNER + c;
    float v = cb[c] + wt.w * p[0];
    if (s >= 1) v += wt.z * p[-DINNER];
    if (s >= 2) v += wt.y * p[-2 * DINNER];
    if (s >= 3) v += wt.x * p[-3 * DINNER];

    float sv = v / (1.f + __expf(-v));          // silu
    xs[idx] = (bf16_t)sv;
    if (c < DSTATE) uT[b * (DSTATE * SEQ) + c * SEQ + s] = sv;
}

// ---------------------------------------------------------------------------
// dt[b,s,e] = softplus( dot(xs[b,s,:], W_dt[e,:]) + b_dt[e] ), e < 16.
// One block per row; writes dtT[b][e][s] fp32 (transposed for the scan).
// ---------------------------------------------------------------------------
__global__ __launch_bounds__(256)
void dt_kernel(const bf16_t* __restrict__ xs, const bf16_t* __restrict__ wdt,
               const float* __restrict__ b_dt, float* __restrict__ dtT)
{
    const int r = blockIdx.x, t = threadIdx.x;
    float acc[DSTATE];
#pragma unroll
    for (int e = 0; e < DSTATE; ++e) acc[e] = 0.f;

#pragma unroll
    for (int i = 0; i < 2; ++i) {
        int c0 = i * 2048 + t * 8;
        bf16x8 xv = *(const bf16x8*)(xs + (size_t)r * DINNER + c0);
        float xf[8];
#pragma unroll
        for (int j = 0; j < 8; ++j) xf[j] = (float)xv[j];
#pragma unroll
        for (int e = 0; e < DSTATE; ++e) {
            bf16x8 wv = *(const bf16x8*)(wdt + e * DINNER + c0);
            float s = 0.f;
#pragma unroll
            for (int j = 0; j < 8; ++j) s += xf[j] * (float)wv[j];
            acc[e] += s;
        }
    }
#pragma unroll
    for (int e = 0; e < DSTATE; ++e)
#pragma unroll
        for (int off = 32; off > 0; off >>= 1) acc[e] += __shfl_down(acc[e], off);

    __shared__ float red[4][DSTATE];
    int w = t >> 6;
    if ((t & 63) == 0) {
#pragma unroll
        for (int e = 0; e < DSTATE; ++e) red[w][e] = acc[e];
    }
    __syncthreads();
    if (t < DSTATE) {
        float tot = red[0][t] + red[1][t] + red[2][t] + red[3][t] + b_dt[t];
        float dt  = (tot > 20.f) ? tot : log1pf(__expf(tot));
        int b = r >> 11, s = r & (SEQ - 1);
        dtT[b * (DSTATE * SEQ) + t * SEQ + s] = dt;
    }
}

// ---------------------------------------------------------------------------
// sequential scan: 32 independent recurrences (2 batches x 16 states).
// lane (b,n): h = h*(1+dt)+u ; ys[b,s] = sum_n A[n]*h[b,s,n] via LDS chunks.
// ---------------------------------------------------------------------------
__global__ void scan_kernel(const float* __restrict__ dtT, const float* __restrict__ uT,
                            const float* __restrict__ A_log, float* __restrict__ result)
{
    constexpr int CH = 128;
    __shared__ float ch[2][CH][17];             // pad 17: conflict-free phase 2
    const int t = threadIdx.x;
    const int b = (t >> 4) & 1;
    const int n = t & 15;

    float An = 0.f, h = 0.f;
    const float *dtp = dtT, *up = uT;
    if (t < 32) {
        An  = -expf(A_log[n]);
        dtp = dtT + b * (DSTATE * SEQ) + n * SEQ;
        up  = uT  + b * (DSTATE * SEQ) + n * SEQ;
    }

    for (int s0 = 0; s0 < SEQ; s0 += CH) {
        if (t < 32) {
            for (int i = 0; i < CH; i += 4) {
                float4 dv = *(const float4*)(dtp + s0 + i);
                float4 uv = *(const float4*)(up + s0 + i);
                h = h * (1.f + dv.x) + uv.x; ch[b][i + 0][n] = h * An;
                h = h * (1.f + dv.y) + uv.y; ch[b][i + 1][n] = h * An;
                h = h * (1.f + dv.z) + uv.z; ch[b][i + 2][n] = h * An;
                h = h * (1.f + dv.w) + uv.w; ch[b][i + 3][n] = h * An;
            }
        }
        __syncthreads();
        for (int j = t; j < 2 * CH; j += 64) {
            int bb = j >> 7, ii = j & (CH - 1);
            float s = 0.f;
#pragma unroll
            for (int n2 = 0; n2 < DSTATE; ++n2) s += ch[bb][ii][n2];
            result[bb * SEQ + s0 + ii] = s;
        }
        __syncthreads();
    }
}

// ---------------------------------------------------------------------------
// launch
// ---------------------------------------------------------------------------
extern "C" void kernel_launch(void* const* d_in, const int* in_sizes, int n_in,
                              void* d_out, int out_size, void* d_ws, size_t ws_size,
                              hipStream_t stream)
{
    const float* x      = (const float*)d_in[0];
    const float* W_in   = (const float*)d_in[1];
    const float* conv_w = (const float*)d_in[2];
    const float* conv_b = (const float*)d_in[3];
    const float* W_dt   = (const float*)d_in[4];
    const float* b_dt   = (const float*)d_in[5];
    const float* A_log  = (const float*)d_in[6];
    const float* W_out  = (const float*)d_in[7];
    float* out = (float*)d_out;

    const size_t MB = 1u << 20;
    char* w = (char*)d_ws;
    // layout (total ~160.7 MB):
    bf16_t* xb   = (bf16_t*)(w);                     // 16 MB  (dead after gemm1)
    bf16_t* wib  = (bf16_t*)(w + 16 * MB);           // 32 MB  (dead after gemm1)
    bf16_t* xs   = (bf16_t*)(w);                     // 32 MB  aliases xb+wib
    bf16_t* wob  = (bf16_t*)(w + 48 * MB);           // 16 MB
    float*  xi   = (float*) (w + 64 * MB);           // 64 MB
    bf16_t* g    = (bf16_t*)(w + 128 * MB);          // 32 MB
    bf16_t* wdtb = (bf16_t*)(w + 160 * MB);          // 128 KB
    float*  uT   = (float*) (w + 160 * MB + 131072);             // 256 KB
    float*  dtT  = (float*) (w + 160 * MB + 131072 + 262144);    // 256 KB
    float*  res  = (float*) (w + 160 * MB + 131072 + 2 * 262144); // 16 KB

    // 1. casts to bf16
    cast_kernel<<<4096, 256, 0, stream>>>(x,     xb,   NROWS * DMODEL);      // 8.4M
    cast_kernel<<<8192, 256, 0, stream>>>(W_in,  wib,  2 * DINNER * DMODEL); // 16.8M
    cast_kernel<<<32,   256, 0, stream>>>(W_dt,  wdtb, DSTATE * DINNER);     // 64K (rows 0..15)
    cast_kernel<<<4096, 256, 0, stream>>>(W_out, wob,  DMODEL * DINNER);     // 8.4M

    // 2. GEMM1: xz = x @ W_in^T  -> xi fp32 | g = sigmoid(gate) bf16
    gemm_bt<0><<<dim3(64, 32), 256, 0, stream>>>(xb, wib, DMODEL, xi, g, nullptr);

    // 3. conv + silu -> xs bf16, uT fp32
    conv_silu_kernel<<<65536, 256, 0, stream>>>(xi, conv_w, conv_b, xs, uT);

    // 4. dt matvec (16 outputs) + softplus -> dtT fp32
    dt_kernel<<<NROWS, 256, 0, stream>>>(xs, wdtb, b_dt, dtT);

    // 5. sequential scan -> res[b*S+s]
    scan_kernel<<<1, 64, 0, stream>>>(dtT, uT, A_log, res);

    // 6. GEMM2: out = (4096*res[row]) * (g @ W_out^T)
    gemm_bt<1><<<dim3(16, 32), 256, 0, stream>>>(g, wob, DINNER, out, nullptr, res);
}

// Round 3
// 606.127 us; speedup vs baseline: 1.0688x; 1.0688x over previous
//
#include <hip/hip_runtime.h>
#include <hip/hip_bf16.h>
#include <math.h>

using bf16_t = __bf16;
using bf16x8 = __attribute__((ext_vector_type(8))) __bf16;
using f32x4  = __attribute__((ext_vector_type(4))) float;

typedef __attribute__((address_space(1))) const void* gas_ptr;
typedef __attribute__((address_space(3))) void*       las_ptr;

// ---------------------------------------------------------------------------
// Problem constants
// ---------------------------------------------------------------------------
#define BATCH    2
#define SEQ      2048
#define DMODEL   2048
#define DINNER   4096
#define DSTATE   16
#define NROWS    (BATCH * SEQ)          // 4096

// ---------------------------------------------------------------------------
// fp32 -> bf16 cast (8 elems / thread)
// ---------------------------------------------------------------------------
__global__ void cast_kernel(const float* __restrict__ src, bf16_t* __restrict__ dst, int n)
{
    int idx = (blockIdx.x * 256 + threadIdx.x) * 8;
    if (idx >= n) return;
    float4 a = *(const float4*)(src + idx);
    float4 b = *(const float4*)(src + idx + 4);
    bf16x8 o;
    o[0] = (bf16_t)a.x; o[1] = (bf16_t)a.y; o[2] = (bf16_t)a.z; o[3] = (bf16_t)a.w;
    o[4] = (bf16_t)b.x; o[5] = (bf16_t)b.y; o[6] = (bf16_t)b.z; o[7] = (bf16_t)b.w;
    *(bf16x8*)(dst + idx) = o;
}

// ---------------------------------------------------------------------------
// bf16 GEMM  C = A(MxK, row-major) * B(NxK, row-major)^T
// 128x128 tile, BK=64, 4 waves, mfma_f32_16x16x32_bf16, 4x4 acc/wave.
// Staging via global_load_lds width=16 (m97 structure) + XOR swizzle:
//   LDS 16B-block position (row, b) holds global K-block b ^ (row&7).
// Store side: per-lane GLOBAL address carries the swizzle (LDS dest must stay
// wave-uniform base + lane*16). Read side: block idx = (ks*4+q) ^ (lo&7)
// -> uniform 8-lanes-per-4-bank-group, same conflict level as a padded tile.
// MODE 0 (GEMM1): N=8192; col<4096 -> xi fp32 ; col>=4096 -> sigmoid -> g bf16
// MODE 1 (GEMM2): N=2048; out[row][col] = acc * (4096 * rowscale[row])
// ---------------------------------------------------------------------------
template <int MODE>
__global__ __launch_bounds__(256)
void gemm_bt(const bf16_t* __restrict__ A, const bf16_t* __restrict__ B, int K,
             float* __restrict__ outf, bf16_t* __restrict__ outg,
             const float* __restrict__ rowscale)
{
    constexpr int LDK = 64;            // unpadded: required by global_load_lds
    __shared__ bf16_t As[128 * LDK];
    __shared__ bf16_t Bs[128 * LDK];

    const int t    = threadIdx.x;
    const int m0   = blockIdx.y * 128;
    const int n0   = blockIdx.x * 128;
    const int w    = t >> 6;
    const int lane = t & 63;
    const int wr   = (w >> 1) * 64;
    const int wc   = (w & 1) * 64;
    const int lo   = lane & 15;
    const int q    = lane >> 4;

    // staging geometry: wave w covers rows [w*32, w*32+32); chunk c = 8 rows.
    // lane i -> row_in_chunk r_l = i>>3 (== row&7 since chunk base % 8 == 0),
    // global col-block = (i&7) ^ r_l  (the swizzle), LDS dest = chunk base.
    const int r_l  = lane >> 3;
    const int cb   = (lane & 7) ^ r_l;                 // swizzled 8-elem block
    const bf16_t* gA = A + (size_t)(m0 + w * 32 + r_l) * K + cb * 8;
    const bf16_t* gB = B + (size_t)(n0 + w * 32 + r_l) * K + cb * 8;

    f32x4 acc[4][4];
#pragma unroll
    for (int i = 0; i < 4; ++i)
#pragma unroll
        for (int j = 0; j < 4; ++j) acc[i][j] = (f32x4){0.f, 0.f, 0.f, 0.f};

    for (int k0 = 0; k0 < K; k0 += 64) {
#pragma unroll
        for (int c = 0; c < 4; ++c) {
            const size_t go     = (size_t)c * 8 * K;      // +8 rows per chunk
            const int    lo_off = (w * 32 + c * 8) * LDK; // wave-uniform
            __builtin_amdgcn_global_load_lds((gas_ptr)(gA + go), (las_ptr)&As[lo_off], 16, 0, 0);
            __builtin_amdgcn_global_load_lds((gas_ptr)(gB + go), (las_ptr)&Bs[lo_off], 16, 0, 0);
        }
        gA += 64; gB += 64;
        __syncthreads();                                  // drains vmcnt too

        const int swz = lo & 7;
#pragma unroll
        for (int ks = 0; ks < 2; ++ks) {
            const int kb = (ks * 4 + q) ^ swz;            // swizzled block idx
            const int kk = kb * 8;
            bf16x8 af[4], bfv[4];
#pragma unroll
            for (int mi = 0; mi < 4; ++mi)
                af[mi] = *(const bf16x8*)&As[(wr + mi * 16 + lo) * LDK + kk];
#pragma unroll
            for (int ni = 0; ni < 4; ++ni)
                bfv[ni] = *(const bf16x8*)&Bs[(wc + ni * 16 + lo) * LDK + kk];
#pragma unroll
            for (int mi = 0; mi < 4; ++mi)
#pragma unroll
                for (int ni = 0; ni < 4; ++ni)
                    acc[mi][ni] = __builtin_amdgcn_mfma_f32_16x16x32_bf16(
                        af[mi], bfv[ni], acc[mi][ni], 0, 0, 0);
        }
        __syncthreads();
    }

    // epilogue: C/D layout col = lane&15, row = quad*4 + reg  [m89/m91 verified]
#pragma unroll
    for (int mi = 0; mi < 4; ++mi) {
#pragma unroll
        for (int ni = 0; ni < 4; ++ni) {
            const int col   = n0 + wc + ni * 16 + lo;
            const int rbase = m0 + wr + mi * 16 + q * 4;
#pragma unroll
            for (int rr = 0; rr < 4; ++rr) {
                float v   = acc[mi][ni][rr];
                int   row = rbase + rr;
                if (MODE == 0) {
                    if (col < DINNER) {
                        outf[(size_t)row * DINNER + col] = v;            // xi fp32
                    } else {
                        float sg = 1.f / (1.f + __expf(-v));             // sigmoid(gate)
                        outg[(size_t)row * DINNER + (col - DINNER)] = (bf16_t)sg;
                    }
                } else {
                    outf[(size_t)row * DMODEL + col] = v * (4096.0f * rowscale[row]);
                }
            }
        }
    }
}

// ---------------------------------------------------------------------------
// depthwise causal conv(4) + SiLU.  Writes xs (bf16, all 4096 ch) and
// uT[b][c][s] fp32 for c<16 (transposed for the scan).
// ---------------------------------------------------------------------------
__global__ void conv_silu_kernel(const float* __restrict__ xi, const float* __restrict__ cw,
                                 const float* __restrict__ cb, bf16_t* __restrict__ xs,
                                 float* __restrict__ uT)
{
    int idx = blockIdx.x * 256 + threadIdx.x;   // < 16,777,216
    int r = idx >> 12;
    int c = idx & 4095;
    int s = r & (SEQ - 1);
    int b = r >> 11;

    float4 wt = *(const float4*)(cw + c * 4);   // taps k=0..3 -> inputs s-3..s
    const float* p = xi + (size_t)r * DINNER + c;
    float v = cb[c] + wt.w * p[0];
    if (s >= 1) v += wt.z * p[-DINNER];
    if (s >= 2) v += wt.y * p[-2 * DINNER];
    if (s >= 3) v += wt.x * p[-3 * DINNER];

    float sv = v / (1.f + __expf(-v));          // silu
    xs[idx] = (bf16_t)sv;
    if (c < DSTATE) uT[b * (DSTATE * SEQ) + c * SEQ + s] = sv;
}

// ---------------------------------------------------------------------------
// dt[b,s,e] = softplus( dot(xs[b,s,:], W_dt[e,:]) + b_dt[e] ), e < 16.
// One block per row; writes dtT[b][e][s] fp32 (transposed for the scan).
// ---------------------------------------------------------------------------
__global__ __launch_bounds__(256)
void dt_kernel(const bf16_t* __restrict__ xs, const bf16_t* __restrict__ wdt,
               const float* __restrict__ b_dt, float* __restrict__ dtT)
{
    const int r = blockIdx.x, t = threadIdx.x;
    float acc[DSTATE];
#pragma unroll
    for (int e = 0; e < DSTATE; ++e) acc[e] = 0.f;

#pragma unroll
    for (int i = 0; i < 2; ++i) {
        int c0 = i * 2048 + t * 8;
        bf16x8 xv = *(const bf16x8*)(xs + (size_t)r * DINNER + c0);
        float xf[8];
#pragma unroll
        for (int j = 0; j < 8; ++j) xf[j] = (float)xv[j];
#pragma unroll
        for (int e = 0; e < DSTATE; ++e) {
            bf16x8 wv = *(const bf16x8*)(wdt + e * DINNER + c0);
            float s = 0.f;
#pragma unroll
            for (int j = 0; j < 8; ++j) s += xf[j] * (float)wv[j];
            acc[e] += s;
        }
    }
#pragma unroll
    for (int e = 0; e < DSTATE; ++e)
#pragma unroll
        for (int off = 32; off > 0; off >>= 1) acc[e] += __shfl_down(acc[e], off);

    __shared__ float red[4][DSTATE];
    int w = t >> 6;
    if ((t & 63) == 0) {
#pragma unroll
        for (int e = 0; e < DSTATE; ++e) red[w][e] = acc[e];
    }
    __syncthreads();
    if (t < DSTATE) {
        float tot = red[0][t] + red[1][t] + red[2][t] + red[3][t] + b_dt[t];
        float dt  = (tot > 20.f) ? tot : log1pf(__expf(tot));
        int b = r >> 11, s = r & (SEQ - 1);
        dtT[b * (DSTATE * SEQ) + t * SEQ + s] = dt;
    }
}

// ---------------------------------------------------------------------------
// sequential scan: 32 independent recurrences (2 batches x 16 states).
// lane (b,n): h = h*(1+dt)+u ; ys[b,s] = sum_n A[n]*h[b,s,n] via LDS chunks.
// ---------------------------------------------------------------------------
__global__ void scan_kernel(const float* __restrict__ dtT, const float* __restrict__ uT,
                            const float* __restrict__ A_log, float* __restrict__ result)
{
    constexpr int CH = 128;
    __shared__ float ch[2][CH][17];             // pad 17: conflict-free phase 2
    const int t = threadIdx.x;
    const int b = (t >> 4) & 1;
    const int n = t & 15;

    float An = 0.f, h = 0.f;
    const float *dtp = dtT, *up = uT;
    if (t < 32) {
        An  = -expf(A_log[n]);
        dtp = dtT + b * (DSTATE * SEQ) + n * SEQ;
        up  = uT  + b * (DSTATE * SEQ) + n * SEQ;
    }

    for (int s0 = 0; s0 < SEQ; s0 += CH) {
        if (t < 32) {
            for (int i = 0; i < CH; i += 4) {
                float4 dv = *(const float4*)(dtp + s0 + i);
                float4 uv = *(const float4*)(up + s0 + i);
                h = h * (1.f + dv.x) + uv.x; ch[b][i + 0][n] = h * An;
                h = h * (1.f + dv.y) + uv.y; ch[b][i + 1][n] = h * An;
                h = h * (1.f + dv.z) + uv.z; ch[b][i + 2][n] = h * An;
                h = h * (1.f + dv.w) + uv.w; ch[b][i + 3][n] = h * An;
            }
        }
        __syncthreads();
        for (int j = t; j < 2 * CH; j += 64) {
            int bb = j >> 7, ii = j & (CH - 1);
            float s = 0.f;
#pragma unroll
            for (int n2 = 0; n2 < DSTATE; ++n2) s += ch[bb][ii][n2];
            result[bb * SEQ + s0 + ii] = s;
        }
        __syncthreads();
    }
}

// ---------------------------------------------------------------------------
// launch
// ---------------------------------------------------------------------------
extern "C" void kernel_launch(void* const* d_in, const int* in_sizes, int n_in,
                              void* d_out, int out_size, void* d_ws, size_t ws_size,
                              hipStream_t stream)
{
    const float* x      = (const float*)d_in[0];
    const float* W_in   = (const float*)d_in[1];
    const float* conv_w = (const float*)d_in[2];
    const float* conv_b = (const float*)d_in[3];
    const float* W_dt   = (const float*)d_in[4];
    const float* b_dt   = (const float*)d_in[5];
    const float* A_log  = (const float*)d_in[6];
    const float* W_out  = (const float*)d_in[7];
    float* out = (float*)d_out;

    const size_t MB = 1u << 20;
    char* w = (char*)d_ws;
    // layout (total ~160.7 MB):
    bf16_t* xb   = (bf16_t*)(w);                     // 16 MB  (dead after gemm1)
    bf16_t* wib  = (bf16_t*)(w + 16 * MB);           // 32 MB  (dead after gemm1)
    bf16_t* xs   = (bf16_t*)(w);                     // 32 MB  aliases xb+wib
    bf16_t* wob  = (bf16_t*)(w + 48 * MB);           // 16 MB
    float*  xi   = (float*) (w + 64 * MB);           // 64 MB
    bf16_t* g    = (bf16_t*)(w + 128 * MB);          // 32 MB
    bf16_t* wdtb = (bf16_t*)(w + 160 * MB);          // 128 KB
    float*  uT   = (float*) (w + 160 * MB + 131072);             // 256 KB
    float*  dtT  = (float*) (w + 160 * MB + 131072 + 262144);    // 256 KB
    float*  res  = (float*) (w + 160 * MB + 131072 + 2 * 262144); // 16 KB

    // 1. casts to bf16
    cast_kernel<<<4096, 256, 0, stream>>>(x,     xb,   NROWS * DMODEL);      // 8.4M
    cast_kernel<<<8192, 256, 0, stream>>>(W_in,  wib,  2 * DINNER * DMODEL); // 16.8M
    cast_kernel<<<32,   256, 0, stream>>>(W_dt,  wdtb, DSTATE * DINNER);     // 64K (rows 0..15)
    cast_kernel<<<4096, 256, 0, stream>>>(W_out, wob,  DMODEL * DINNER);     // 8.4M

    // 2. GEMM1: xz = x @ W_in^T  -> xi fp32 | g = sigmoid(gate) bf16
    gemm_bt<0><<<dim3(64, 32), 256, 0, stream>>>(xb, wib, DMODEL, xi, g, nullptr);

    // 3. conv + silu -> xs bf16, uT fp32
    conv_silu_kernel<<<65536, 256, 0, stream>>>(xi, conv_w, conv_b, xs, uT);

    // 4. dt matvec (16 outputs) + softplus -> dtT fp32
    dt_kernel<<<NROWS, 256, 0, stream>>>(xs, wdtb, b_dt, dtT);

    // 5. sequential scan -> res[b*S+s]
    scan_kernel<<<1, 64, 0, stream>>>(dtT, uT, A_log, res);

    // 6. GEMM2: out = (4096*res[row]) * (g @ W_out^T)
    gemm_bt<1><<<dim3(16, 32), 256, 0, stream>>>(g, wob, DINNER, out, nullptr, res);
}